// Round 6
// baseline (53.445 us; speedup 1.0000x reference)
//
#include <hip/hip_runtime.h>
#include <hip/hip_fp16.h>

// MultiScaleRoIAlign (round 10): two-pass; repack tile 64c x 128hw via
// global_load_lds -> 512B contiguous read runs per row-visit (2x round 9).
// Single-variable test of the DRAM read-granularity hypothesis: rounds 0/1/5
// (256B runs) all pinned at ~2.2 TB/s regardless of instruction count,
// pipeline depth, or occupancy. Machinery (gll + inverse-swizzled per-lane
// source + involution read + c64-plane output + pass 2) is byte-identical to
// the verified round-9 kernel; only tile geometry changed.

#define ROI_OUT 7
#define NSAMP   14
#define C_TOT   256
#define N_PER_B 256
#define BINS    49
#define TOT_HW  53125          // 40000 + 10000 + 2500 + 625 per image

// hw-tile counts per level (ceil(HW/128)): 313, 79, 20, 5 -> prefix 313,392,412,417
#define NTILE_X 417

// XOR swizzle on 4-float granules within a row (involution, 4-aligned)
#define SWZG(c) ((((c) ^ ((c) >> 3)) & 7) << 2)

typedef const __attribute__((address_space(1))) float* gas1_t;
typedef __attribute__((address_space(3))) float*       las3_t;

// ---------------- pass 1: transpose to c64-plane fp16 ----------------
__global__ __launch_bounds__(256)
void repack_kernel(const float* __restrict__ f0, const float* __restrict__ f1,
                   const float* __restrict__ f2, const float* __restrict__ f3,
                   __half* __restrict__ ws)
{
    // linear [c][p] (64 x 128 fp32); slot (c,p) holds feat[c][hw0 + (p ^ SWZG(c))]
    __shared__ float tile[64 * 128];   // 32 KB

    const int tx = blockIdx.x;
    const float* feat; int HW, base, hw0;
    if (tx < 313)      { feat = f0; HW = 40000; base = 0;     hw0 = tx * 128; }
    else if (tx < 392) { feat = f1; HW = 10000; base = 40000; hw0 = (tx - 313) * 128; }
    else if (tx < 412) { feat = f2; HW = 2500;  base = 50000; hw0 = (tx - 392) * 128; }
    else               { feat = f3; HW = 625;   base = 52500; hw0 = (tx - 412) * 128; }

    const int g  = blockIdx.y;          // c-group 0..3
    const int c0 = g * 64;
    const int b  = blockIdx.z;
    const float* src = feat + ((size_t)(b * C_TOT + c0)) * (size_t)HW + hw0;

    const int t = threadIdx.x;
    const int w = t >> 6;               // wave 0..3
    const int l = t & 63;

    const bool fast = (hw0 + 128 <= HW) && ((HW & 3) == 0);

    if (fast) {
        // instr q (0..31) covers rows 2q,2q+1: lanes 0-31 -> row 2q (512B run),
        // lanes 32-63 -> row 2q+1 (512B run). Dest linear: tile + q*256 floats.
        const int rq = l >> 5;           // row within pair
        const int gr = l & 31;           // 16B granule within row
        #pragma unroll
        for (int i = 0; i < 8; ++i) {
            int q  = 8 * w + i;
            int c  = 2 * q + rq;
            int hw = (gr * 4) ^ SWZG(c); // inverse-swizzled source offset
            const float* gp = src + (size_t)c * HW + hw;
            __builtin_amdgcn_global_load_lds((gas1_t)(const void*)gp,
                                             (las3_t)(void*)(tile + q * 256),
                                             16, 0, 0);
        }
    } else {
        // tails + level 3 (HW=625, rows not 16B-aligned): guarded scalar stage.
        // granule G = c*32 + p; slot floats c*128 + p*4 + j hold src hw
        // ((p*4)^SWZG(c)) + j  (== ((p*4)+j)^SWZG since SWZG is 4-aligned).
        for (int G = t; G < 64 * 32; G += 256) {
            int c  = G >> 5;
            int p  = G & 31;
            int sh = (p * 4) ^ SWZG(c);
            #pragma unroll
            for (int j = 0; j < 4; ++j) {
                int srchw = sh + j;
                float v = (srchw < HW - hw0) ? src[(size_t)c * HW + srchw] : 0.0f;
                tile[c * 128 + p * 4 + j] = v;
            }
        }
    }
    __syncthreads();   // drains vmcnt (gll) / lgkmcnt before barrier

    // read transposed + convert + contiguous fp16 store.
    // lane: c4=(t&15)*4 (8B out), 16 lanes cover one 128B row; wave writes 4
    // consecutive rows = 512B contiguous per iteration; 8 iterations = 128 rows.
    __half* plane = ws + ((size_t)b * TOT_HW + base) * C_TOT
                       + (size_t)g * (size_t)HW * 64 + (size_t)hw0 * 64;
    const int c4 = (t & 15) * 4;
    const int r0 = t >> 4;              // 0..15
    #pragma unroll
    for (int i = 0; i < 8; ++i) {
        int hw = 16 * i + r0;
        if (hw0 + hw < HW) {
            float v0 = tile[(c4 + 0) * 128 + (hw ^ SWZG(c4 + 0))];
            float v1 = tile[(c4 + 1) * 128 + (hw ^ SWZG(c4 + 1))];
            float v2 = tile[(c4 + 2) * 128 + (hw ^ SWZG(c4 + 2))];
            float v3 = tile[(c4 + 3) * 128 + (hw ^ SWZG(c4 + 3))];
            __half2 hh[2];
            hh[0] = __floats2half2_rn(v0, v1);
            hh[1] = __floats2half2_rn(v2, v3);
            *(float2*)(plane + (size_t)hw * 64 + c4) = *(const float2*)hh;
        }
    }
}

// ---------------- pass 2: per-roi pooled gather (c64-plane, verified) ----------------
__global__ __launch_bounds__(256)
void msroi_main(const __half* __restrict__ ws, const float* __restrict__ boxes,
                float* __restrict__ out)
{
    __shared__ float oacc[C_TOT * BINS];   // [c][bin], 50176 B
    __shared__ int4  pY[NSAMP], pX[NSAMP];

    const int tid = threadIdx.x;
    const int roi = blockIdx.x;
    const int b   = roi >> 8;

    const float* bxp = boxes + (size_t)roi * 4;
    float bx1 = bxp[0], by1 = bxp[1], bx2 = bxp[2], by2 = bxp[3];
    float area = (bx2 - bx1) * (by2 - by1);
    float s    = sqrtf(area);
    float lvlf = floorf(4.0f + log2f(s * (1.0f / 224.0f)) + 1e-6f);
    lvlf = fminf(fmaxf(lvlf, 2.0f), 5.0f);
    int level = (int)lvlf - 2;

    int H, W, lvbase; float scale;
    switch (level) {
        case 0:  H = 200; W = 200; lvbase = 0;     scale = 0.25f;    break;
        case 1:  H = 100; W = 100; lvbase = 40000; scale = 0.125f;   break;
        case 2:  H = 50;  W = 50;  lvbase = 50000; scale = 0.0625f;  break;
        default: H = 25;  W = 25;  lvbase = 52500; scale = 0.03125f; break;
    }

    float x1 = bx1 * scale, y1 = by1 * scale;
    float roi_w = fmaxf(bx2 * scale - x1, 1.0f);
    float roi_h = fmaxf(by2 * scale - y1, 1.0f);
    float bin_w = roi_w * (1.0f / ROI_OUT);
    float bin_h = roi_h * (1.0f / ROI_OUT);

    if (tid < 2 * NSAMP) {
        bool isy = tid >= NSAMP;
        int  j   = isy ? tid - NSAMP : tid;
        int  pb  = j >> 1, sub = j & 1;
        float start = isy ? y1 : x1;
        float bsz   = isy ? bin_h : bin_w;
        int   lim   = isy ? H : W;
        float ss = start + (float)pb * bsz + ((float)sub + 0.5f) * bsz * 0.5f;
        float v  = (ss >= -1.0f && ss <= (float)lim) ? 1.0f : 0.0f;
        float cc = fminf(fmaxf(ss, 0.0f), (float)lim - 1.0f);
        int   i0 = (int)floorf(cc);
        int   i1 = min(i0 + 1, lim - 1);
        float l  = cc - (float)i0;
        int4 pk; pk.x = i0; pk.y = i1;
        pk.z = __float_as_int(l); pk.w = __float_as_int(v);
        if (isy) pY[j] = pk; else pX[j] = pk;
    }
    __syncthreads();

    const int wave = tid >> 6;
    const int lane = tid & 63;
    const int c    = lane * 4;
    const __half* gbase = ws + ((size_t)b * TOT_HW + lvbase) * C_TOT
                             + (size_t)(lane >> 4) * (size_t)(H * W) * 64
                             + (lane & 15) * 4;

    for (int bin = wave; bin < BINS; bin += 4) {
        int ph = bin / ROI_OUT;
        int pw = bin - ph * ROI_OUT;
        float a0 = 0.f, a1 = 0.f, a2 = 0.f, a3 = 0.f;

        #pragma unroll
        for (int sy = 0; sy < 2; ++sy) {
            int4 py  = pY[2 * ph + sy];
            float ly = __int_as_float(py.z);
            float vy = __int_as_float(py.w);
            float hy = 1.0f - ly;
            #pragma unroll
            for (int sx = 0; sx < 2; ++sx) {
                int4 px  = pX[2 * pw + sx];
                float lx = __int_as_float(px.z);
                float vv = vy * __int_as_float(px.w);
                float hx = 1.0f - lx;
                float w00 = vv * hy * hx, w01 = vv * hy * lx;
                float w10 = vv * ly * hx, w11 = vv * ly * lx;

                const __half2* p00 = (const __half2*)(gbase + (size_t)(py.x * W + px.x) * 64);
                const __half2* p01 = (const __half2*)(gbase + (size_t)(py.x * W + px.y) * 64);
                const __half2* p10 = (const __half2*)(gbase + (size_t)(py.y * W + px.x) * 64);
                const __half2* p11 = (const __half2*)(gbase + (size_t)(py.y * W + px.y) * 64);

                float2 g0, g1;
                g0 = __half22float2(p00[0]); g1 = __half22float2(p00[1]);
                a0 += w00 * g0.x; a1 += w00 * g0.y; a2 += w00 * g1.x; a3 += w00 * g1.y;
                g0 = __half22float2(p01[0]); g1 = __half22float2(p01[1]);
                a0 += w01 * g0.x; a1 += w01 * g0.y; a2 += w01 * g1.x; a3 += w01 * g1.y;
                g0 = __half22float2(p10[0]); g1 = __half22float2(p10[1]);
                a0 += w10 * g0.x; a1 += w10 * g0.y; a2 += w10 * g1.x; a3 += w10 * g1.y;
                g0 = __half22float2(p11[0]); g1 = __half22float2(p11[1]);
                a0 += w11 * g0.x; a1 += w11 * g0.y; a2 += w11 * g1.x; a3 += w11 * g1.y;
            }
        }
        oacc[(c + 0) * BINS + bin] = a0 * 0.25f;
        oacc[(c + 1) * BINS + bin] = a1 * 0.25f;
        oacc[(c + 2) * BINS + bin] = a2 * 0.25f;
        oacc[(c + 3) * BINS + bin] = a3 * 0.25f;
    }
    __syncthreads();

    float4*       o4 = (float4*)(out + (size_t)roi * (C_TOT * BINS));
    const float4* s4 = (const float4*)oacc;
    for (int j = tid; j < (C_TOT * BINS) / 4; j += 256) o4[j] = s4[j];
}

// ---------------- fallback: direct gather (NCHW fp32, no ws) ----------------
__global__ __launch_bounds__(256)
void msroi_direct(const float* __restrict__ f0, const float* __restrict__ f1,
                  const float* __restrict__ f2, const float* __restrict__ f3,
                  const float* __restrict__ boxes, float* __restrict__ out, int total)
{
    int e = blockIdx.x * 256 + threadIdx.x;
    if (e >= total) return;
    int bin = e % BINS;
    int c   = (e / BINS) % C_TOT;
    int roi = e / (BINS * C_TOT);
    int b   = roi / N_PER_B;

    const float* bx = boxes + (size_t)roi * 4;
    float bx1 = bx[0], by1 = bx[1], bx2 = bx[2], by2 = bx[3];
    float area = (bx2 - bx1) * (by2 - by1);
    float s    = sqrtf(area);
    float lvlf = floorf(4.0f + log2f(s * (1.0f / 224.0f)) + 1e-6f);
    lvlf = fminf(fmaxf(lvlf, 2.0f), 5.0f);
    int level = (int)lvlf - 2;

    const float* feat; int H, W; float scale;
    switch (level) {
        case 0:  feat = f0; H = 200; W = 200; scale = 0.25f;    break;
        case 1:  feat = f1; H = 100; W = 100; scale = 0.125f;   break;
        case 2:  feat = f2; H = 50;  W = 50;  scale = 0.0625f;  break;
        default: feat = f3; H = 25;  W = 25;  scale = 0.03125f; break;
    }
    float x1 = bx1 * scale, y1 = by1 * scale;
    float roi_w = fmaxf(bx2 * scale - x1, 1.0f);
    float roi_h = fmaxf(by2 * scale - y1, 1.0f);
    float bin_w = roi_w * (1.0f / ROI_OUT);
    float bin_h = roi_h * (1.0f / ROI_OUT);
    int ph = bin / ROI_OUT, pw = bin - ph * ROI_OUT;
    const float* plane = feat + ((size_t)(b * C_TOT + c)) * (size_t)(H * W);
    float Hf = (float)H, Wf = (float)W, acc = 0.0f;
    #pragma unroll
    for (int sy = 0; sy < 2; ++sy) {
        float ys = y1 + (float)ph * bin_h + ((float)sy + 0.5f) * bin_h * 0.5f;
        float vy = (ys >= -1.0f && ys <= Hf) ? 1.0f : 0.0f;
        float y  = fminf(fmaxf(ys, 0.0f), Hf - 1.0f);
        int   y0 = (int)floorf(y);
        int   y1i = min(y0 + 1, H - 1);
        float ly = y - (float)y0, hy = 1.0f - ly;
        int ro0 = y0 * W, ro1 = y1i * W;
        #pragma unroll
        for (int sx = 0; sx < 2; ++sx) {
            float xs = x1 + (float)pw * bin_w + ((float)sx + 0.5f) * bin_w * 0.5f;
            float vx = (xs >= -1.0f && xs <= Wf) ? 1.0f : 0.0f;
            float x  = fminf(fmaxf(xs, 0.0f), Wf - 1.0f);
            int   x0 = (int)floorf(x);
            int   x1i = min(x0 + 1, W - 1);
            float lx = x - (float)x0, hx = 1.0f - lx;
            float v00 = plane[ro0 + x0],  v01 = plane[ro0 + x1i];
            float v10 = plane[ro1 + x0],  v11 = plane[ro1 + x1i];
            acc += vy * vx * (hy * (hx * v00 + lx * v01) + ly * (hx * v10 + lx * v11));
        }
    }
    out[e] = acc * 0.25f;
}

extern "C" void kernel_launch(void* const* d_in, const int* in_sizes, int n_in,
                              void* d_out, int out_size, void* d_ws, size_t ws_size,
                              hipStream_t stream)
{
    const float* f0    = (const float*)d_in[0];
    const float* f1    = (const float*)d_in[1];
    const float* f2    = (const float*)d_in[2];
    const float* f3    = (const float*)d_in[3];
    const float* boxes = (const float*)d_in[4];
    float* out = (float*)d_out;

    const size_t ws_needed = (size_t)2 * TOT_HW * C_TOT * sizeof(__half); // 54.4 MB
    if (ws_size >= ws_needed) {
        __half* ws = (__half*)d_ws;
        hipLaunchKernelGGL(repack_kernel, dim3(NTILE_X, 4, 2), dim3(256), 0, stream,
                           f0, f1, f2, f3, ws);
        hipLaunchKernelGGL(msroi_main, dim3(2 * N_PER_B), dim3(256), 0, stream,
                           ws, boxes, out);
    } else {
        int total = out_size;
        hipLaunchKernelGGL(msroi_direct, dim3((total + 255) / 256), dim3(256), 0, stream,
                           f0, f1, f2, f3, boxes, out, total);
    }
}

// Round 7
// 49.616 us; speedup vs baseline: 1.0772x; 1.0772x over previous
//
#include <hip/hip_runtime.h>
#include <hip/hip_fp16.h>

// MultiScaleRoIAlign (round 11): persistent pipelined repack.
// r0-r6 post-mortems: repack pinned at ~2.2 TB/s across instruction count,
// stream shape, gll queue depth, and run length. Remaining theory: per-block
// latency serialization (each short block = issue -> full drain -> store ->
// exit; ~1 HBM latency per block, ~13 block generations per CU = ~45us).
// Fix: persistent blocks, ~7 units each, double-buffered LDS, counted
// s_waitcnt vmcnt(N) + raw s_barrier (no vmcnt(0) drain in loop). Unit
// geometry + gll inverse-swizzle + c64-plane output = round-5 verified code.

#define ROI_OUT 7
#define NSAMP   14
#define C_TOT   256
#define N_PER_B 256
#define BINS    49
#define TOT_HW  53125          // 40000 + 10000 + 2500 + 625 per image

// fast units per (g,b): L0 625 + L1 156 + L2 39 = 820 (64-hw tiles, 16B rows)
// scalar units per (g,b): L1 tail + L2 tail + 10 L3 tiles = 12
#define FAST_PER_GB   820
#define CHUNK         7
#define FBLK_PER_GB   118      // 118*7 = 826 >= 820
#define NFASTBLK      (FBLK_PER_GB * 8)    // 944
#define NSCALBLK      (12 * 8)             // 96
#define NBLK          (NFASTBLK + NSCALBLK)

#define SWZG(c) ((((c) ^ ((c) >> 3)) & 7) << 2)

typedef const __attribute__((address_space(1))) float* gas1_t;
typedef __attribute__((address_space(3))) float*       las3_t;

#define WAITV(n) asm volatile("s_waitcnt vmcnt(" #n ")" ::: "memory")
#define BAR()    asm volatile("s_barrier" ::: "memory")

struct UnitGeom { const float* feat; int HW; int base; int hw0; };

__device__ __forceinline__ UnitGeom fast_geom(int f, const float* f0,
                                              const float* f1, const float* f2)
{
    UnitGeom u;
    if (f < 625)      { u.feat = f0; u.HW = 40000; u.base = 0;     u.hw0 = f * 64; }
    else if (f < 781) { u.feat = f1; u.HW = 10000; u.base = 40000; u.hw0 = (f - 625) * 64; }
    else              { u.feat = f2; u.HW = 2500;  u.base = 50000; u.hw0 = (f - 781) * 64; }
    return u;
}

// issue 16 global_load_lds_dwordx4 for one 64c x 64hw unit (round-5 verified)
__device__ __forceinline__ void unit_issue(const float* src, int HW, int w, int l,
                                           float* buf)
{
    const int cq = l >> 4;           // 0..3
    const int hl = (l & 15) * 4;     // hw quad
    #pragma unroll
    for (int i = 0; i < 4; ++i) {
        int q = 4 * w + i;
        int c = 4 * q + cq;
        const float* gp = src + (size_t)c * HW + (hl ^ SWZG(c));
        __builtin_amdgcn_global_load_lds((gas1_t)(const void*)gp,
                                         (las3_t)(void*)(buf + q * 256),
                                         16, 0, 0);
    }
}

// read transposed + convert + contiguous fp16 store (round-5 verified)
__device__ __forceinline__ void unit_store(const float* buf, __half* plane,
                                           int hw0, int HW, int w, int l)
{
    const int c4 = (l & 15) * 4;
    #pragma unroll
    for (int i = 0; i < 4; ++i) {
        int hw = 16 * w + 4 * i + (l >> 4);
        if (hw0 + hw < HW) {
            float v0 = buf[(c4 + 0) * 64 + (hw ^ SWZG(c4 + 0))];
            float v1 = buf[(c4 + 1) * 64 + (hw ^ SWZG(c4 + 1))];
            float v2 = buf[(c4 + 2) * 64 + (hw ^ SWZG(c4 + 2))];
            float v3 = buf[(c4 + 3) * 64 + (hw ^ SWZG(c4 + 3))];
            __half2 hh[2];
            hh[0] = __floats2half2_rn(v0, v1);
            hh[1] = __floats2half2_rn(v2, v3);
            *(float2*)(plane + (size_t)hw * 64 + c4) = *(const float2*)hh;
        }
    }
}

__global__ __launch_bounds__(256)
void repack_kernel(const float* __restrict__ f0, const float* __restrict__ f1,
                   const float* __restrict__ f2, const float* __restrict__ f3,
                   __half* __restrict__ ws)
{
    __shared__ float tileA[64 * 64];   // 16 KB
    __shared__ float tileB[64 * 64];   // 16 KB

    const int t = threadIdx.x;
    const int w = t >> 6;
    const int l = t & 63;
    const int p = blockIdx.x;

    if (p < NFASTBLK) {
        // ---------------- persistent pipelined fast path ----------------
        const int gb = p / FBLK_PER_GB;
        const int k  = p - gb * FBLK_PER_GB;
        const int g  = gb >> 1;
        const int b  = gb & 1;
        const int fbeg = k * CHUNK;
        const int fend = min(fbeg + CHUNK, FAST_PER_GB);
        const int n    = fend - fbeg;
        if (n <= 0) return;

        const int c0 = g * 64;

        // per-unit source base: feat + (b*C_TOT + c0)*HW + hw0
        UnitGeom u0 = fast_geom(fbeg, f0, f1, f2);
        unit_issue(u0.feat + ((size_t)(b * C_TOT + c0)) * (size_t)u0.HW + u0.hw0,
                   u0.HW, w, l, tileA);

        for (int i = 0; i < n; ++i) {
            float* cur = (i & 1) ? tileB : tileA;
            float* nxt = (i & 1) ? tileA : tileB;
            const bool hn = (i + 1 < n);

            if (hn) {
                UnitGeom un = fast_geom(fbeg + i + 1, f0, f1, f2);
                unit_issue(un.feat + ((size_t)(b * C_TOT + c0)) * (size_t)un.HW + un.hw0,
                           un.HW, w, l, nxt);
            }
            // counted wait: younger ops = (hn? 4 gll) + (i>0? 4 stores)
            if (i == 0) { if (hn) WAITV(4); else WAITV(0); }
            else        { if (hn) WAITV(8); else WAITV(4); }
            BAR();                                    // cur fully in LDS

            UnitGeom uc = fast_geom(fbeg + i, f0, f1, f2);
            __half* plane = ws + ((size_t)b * TOT_HW + uc.base) * C_TOT
                               + (size_t)g * (size_t)uc.HW * 64
                               + (size_t)uc.hw0 * 64;
            unit_store(cur, plane, uc.hw0, uc.HW, w, l);
            BAR();                                    // cur reusable for gll
        }
    } else {
        // ---------------- scalar tail path (plain, 96 blocks) ----------------
        const int su = p - NFASTBLK;
        const int gb = su / 12;
        const int s  = su - gb * 12;
        const int g  = gb >> 1;
        const int b  = gb & 1;
        const int c0 = g * 64;

        const float* feat; int HW, base, hw0;
        if (s == 0)      { feat = f1; HW = 10000; base = 40000; hw0 = 9984; }
        else if (s == 1) { feat = f2; HW = 2500;  base = 50000; hw0 = 2496; }
        else             { feat = f3; HW = 625;   base = 52500; hw0 = (s - 2) * 64; }

        const float* src = feat + ((size_t)(b * C_TOT + c0)) * (size_t)HW + hw0;

        // guarded scalar stage into tileA (round-5 verified slow path)
        for (int G = t; G < 64 * 16; G += 256) {
            int c  = G >> 4;
            int q  = G & 15;
            int sh = (q * 4) ^ SWZG(c);
            #pragma unroll
            for (int j = 0; j < 4; ++j) {
                int srchw = sh + j;
                float v = (srchw < HW - hw0) ? src[(size_t)c * HW + srchw] : 0.0f;
                tileA[c * 64 + q * 4 + j] = v;
            }
        }
        __syncthreads();

        __half* plane = ws + ((size_t)b * TOT_HW + base) * C_TOT
                           + (size_t)g * (size_t)HW * 64 + (size_t)hw0 * 64;
        unit_store(tileA, plane, hw0, HW, w, l);
    }
}

// ---------------- pass 2: per-roi pooled gather (c64-plane, verified) ----------------
__global__ __launch_bounds__(256)
void msroi_main(const __half* __restrict__ ws, const float* __restrict__ boxes,
                float* __restrict__ out)
{
    __shared__ float oacc[C_TOT * BINS];   // [c][bin], 50176 B
    __shared__ int4  pY[NSAMP], pX[NSAMP];

    const int tid = threadIdx.x;
    const int roi = blockIdx.x;
    const int b   = roi >> 8;

    const float* bxp = boxes + (size_t)roi * 4;
    float bx1 = bxp[0], by1 = bxp[1], bx2 = bxp[2], by2 = bxp[3];
    float area = (bx2 - bx1) * (by2 - by1);
    float s    = sqrtf(area);
    float lvlf = floorf(4.0f + log2f(s * (1.0f / 224.0f)) + 1e-6f);
    lvlf = fminf(fmaxf(lvlf, 2.0f), 5.0f);
    int level = (int)lvlf - 2;

    int H, W, lvbase; float scale;
    switch (level) {
        case 0:  H = 200; W = 200; lvbase = 0;     scale = 0.25f;    break;
        case 1:  H = 100; W = 100; lvbase = 40000; scale = 0.125f;   break;
        case 2:  H = 50;  W = 50;  lvbase = 50000; scale = 0.0625f;  break;
        default: H = 25;  W = 25;  lvbase = 52500; scale = 0.03125f; break;
    }

    float x1 = bx1 * scale, y1 = by1 * scale;
    float roi_w = fmaxf(bx2 * scale - x1, 1.0f);
    float roi_h = fmaxf(by2 * scale - y1, 1.0f);
    float bin_w = roi_w * (1.0f / ROI_OUT);
    float bin_h = roi_h * (1.0f / ROI_OUT);

    if (tid < 2 * NSAMP) {
        bool isy = tid >= NSAMP;
        int  j   = isy ? tid - NSAMP : tid;
        int  pb  = j >> 1, sub = j & 1;
        float start = isy ? y1 : x1;
        float bsz   = isy ? bin_h : bin_w;
        int   lim   = isy ? H : W;
        float ss = start + (float)pb * bsz + ((float)sub + 0.5f) * bsz * 0.5f;
        float v  = (ss >= -1.0f && ss <= (float)lim) ? 1.0f : 0.0f;
        float cc = fminf(fmaxf(ss, 0.0f), (float)lim - 1.0f);
        int   i0 = (int)floorf(cc);
        int   i1 = min(i0 + 1, lim - 1);
        float l  = cc - (float)i0;
        int4 pk; pk.x = i0; pk.y = i1;
        pk.z = __float_as_int(l); pk.w = __float_as_int(v);
        if (isy) pY[j] = pk; else pX[j] = pk;
    }
    __syncthreads();

    const int wave = tid >> 6;
    const int lane = tid & 63;
    const int c    = lane * 4;
    const __half* gbase = ws + ((size_t)b * TOT_HW + lvbase) * C_TOT
                             + (size_t)(lane >> 4) * (size_t)(H * W) * 64
                             + (lane & 15) * 4;

    for (int bin = wave; bin < BINS; bin += 4) {
        int ph = bin / ROI_OUT;
        int pw = bin - ph * ROI_OUT;
        float a0 = 0.f, a1 = 0.f, a2 = 0.f, a3 = 0.f;

        #pragma unroll
        for (int sy = 0; sy < 2; ++sy) {
            int4 py  = pY[2 * ph + sy];
            float ly = __int_as_float(py.z);
            float vy = __int_as_float(py.w);
            float hy = 1.0f - ly;
            #pragma unroll
            for (int sx = 0; sx < 2; ++sx) {
                int4 px  = pX[2 * pw + sx];
                float lx = __int_as_float(px.z);
                float vv = vy * __int_as_float(px.w);
                float hx = 1.0f - lx;
                float w00 = vv * hy * hx, w01 = vv * hy * lx;
                float w10 = vv * ly * hx, w11 = vv * ly * lx;

                const __half2* p00 = (const __half2*)(gbase + (size_t)(py.x * W + px.x) * 64);
                const __half2* p01 = (const __half2*)(gbase + (size_t)(py.x * W + px.y) * 64);
                const __half2* p10 = (const __half2*)(gbase + (size_t)(py.y * W + px.x) * 64);
                const __half2* p11 = (const __half2*)(gbase + (size_t)(py.y * W + px.y) * 64);

                float2 g0, g1;
                g0 = __half22float2(p00[0]); g1 = __half22float2(p00[1]);
                a0 += w00 * g0.x; a1 += w00 * g0.y; a2 += w00 * g1.x; a3 += w00 * g1.y;
                g0 = __half22float2(p01[0]); g1 = __half22float2(p01[1]);
                a0 += w01 * g0.x; a1 += w01 * g0.y; a2 += w01 * g1.x; a3 += w01 * g1.y;
                g0 = __half22float2(p10[0]); g1 = __half22float2(p10[1]);
                a0 += w10 * g0.x; a1 += w10 * g0.y; a2 += w10 * g1.x; a3 += w10 * g1.y;
                g0 = __half22float2(p11[0]); g1 = __half22float2(p11[1]);
                a0 += w11 * g0.x; a1 += w11 * g0.y; a2 += w11 * g1.x; a3 += w11 * g1.y;
            }
        }
        oacc[(c + 0) * BINS + bin] = a0 * 0.25f;
        oacc[(c + 1) * BINS + bin] = a1 * 0.25f;
        oacc[(c + 2) * BINS + bin] = a2 * 0.25f;
        oacc[(c + 3) * BINS + bin] = a3 * 0.25f;
    }
    __syncthreads();

    float4*       o4 = (float4*)(out + (size_t)roi * (C_TOT * BINS));
    const float4* s4 = (const float4*)oacc;
    for (int j = tid; j < (C_TOT * BINS) / 4; j += 256) o4[j] = s4[j];
}

// ---------------- fallback: direct gather (NCHW fp32, no ws) ----------------
__global__ __launch_bounds__(256)
void msroi_direct(const float* __restrict__ f0, const float* __restrict__ f1,
                  const float* __restrict__ f2, const float* __restrict__ f3,
                  const float* __restrict__ boxes, float* __restrict__ out, int total)
{
    int e = blockIdx.x * 256 + threadIdx.x;
    if (e >= total) return;
    int bin = e % BINS;
    int c   = (e / BINS) % C_TOT;
    int roi = e / (BINS * C_TOT);
    int b   = roi / N_PER_B;

    const float* bx = boxes + (size_t)roi * 4;
    float bx1 = bx[0], by1 = bx[1], bx2 = bx[2], by2 = bx[3];
    float area = (bx2 - bx1) * (by2 - by1);
    float s    = sqrtf(area);
    float lvlf = floorf(4.0f + log2f(s * (1.0f / 224.0f)) + 1e-6f);
    lvlf = fminf(fmaxf(lvlf, 2.0f), 5.0f);
    int level = (int)lvlf - 2;

    const float* feat; int H, W; float scale;
    switch (level) {
        case 0:  feat = f0; H = 200; W = 200; scale = 0.25f;    break;
        case 1:  feat = f1; H = 100; W = 100; scale = 0.125f;   break;
        case 2:  feat = f2; H = 50;  W = 50;  scale = 0.0625f;  break;
        default: feat = f3; H = 25;  W = 25;  scale = 0.03125f; break;
    }
    float x1 = bx1 * scale, y1 = by1 * scale;
    float roi_w = fmaxf(bx2 * scale - x1, 1.0f);
    float roi_h = fmaxf(by2 * scale - y1, 1.0f);
    float bin_w = roi_w * (1.0f / ROI_OUT);
    float bin_h = roi_h * (1.0f / ROI_OUT);
    int ph = bin / ROI_OUT, pw = bin - ph * ROI_OUT;
    const float* plane = feat + ((size_t)(b * C_TOT + c)) * (size_t)(H * W);
    float Hf = (float)H, Wf = (float)W, acc = 0.0f;
    #pragma unroll
    for (int sy = 0; sy < 2; ++sy) {
        float ys = y1 + (float)ph * bin_h + ((float)sy + 0.5f) * bin_h * 0.5f;
        float vy = (ys >= -1.0f && ys <= Hf) ? 1.0f : 0.0f;
        float y  = fminf(fmaxf(ys, 0.0f), Hf - 1.0f);
        int   y0 = (int)floorf(y);
        int   y1i = min(y0 + 1, H - 1);
        float ly = y - (float)y0, hy = 1.0f - ly;
        int ro0 = y0 * W, ro1 = y1i * W;
        #pragma unroll
        for (int sx = 0; sx < 2; ++sx) {
            float xs = x1 + (float)pw * bin_w + ((float)sx + 0.5f) * bin_w * 0.5f;
            float vx = (xs >= -1.0f && xs <= Wf) ? 1.0f : 0.0f;
            float x  = fminf(fmaxf(xs, 0.0f), Wf - 1.0f);
            int   x0 = (int)floorf(x);
            int   x1i = min(x0 + 1, W - 1);
            float lx = x - (float)x0, hx = 1.0f - lx;
            float v00 = plane[ro0 + x0],  v01 = plane[ro0 + x1i];
            float v10 = plane[ro1 + x0],  v11 = plane[ro1 + x1i];
            acc += vy * vx * (hy * (hx * v00 + lx * v01) + ly * (hx * v10 + lx * v11));
        }
    }
    out[e] = acc * 0.25f;
}

extern "C" void kernel_launch(void* const* d_in, const int* in_sizes, int n_in,
                              void* d_out, int out_size, void* d_ws, size_t ws_size,
                              hipStream_t stream)
{
    const float* f0    = (const float*)d_in[0];
    const float* f1    = (const float*)d_in[1];
    const float* f2    = (const float*)d_in[2];
    const float* f3    = (const float*)d_in[3];
    const float* boxes = (const float*)d_in[4];
    float* out = (float*)d_out;

    const size_t ws_needed = (size_t)2 * TOT_HW * C_TOT * sizeof(__half); // 54.4 MB
    if (ws_size >= ws_needed) {
        __half* ws = (__half*)d_ws;
        hipLaunchKernelGGL(repack_kernel, dim3(NBLK), dim3(256), 0, stream,
                           f0, f1, f2, f3, ws);
        hipLaunchKernelGGL(msroi_main, dim3(2 * N_PER_B), dim3(256), 0, stream,
                           ws, boxes, out);
    } else {
        int total = out_size;
        hipLaunchKernelGGL(msroi_direct, dim3((total + 255) / 256), dim3(256), 0, stream,
                           f0, f1, f2, f3, boxes, out, total);
    }
}